// Round 15
// baseline (268.568 us; speedup 1.0000x reference)
//
#include <hip/hip_runtime.h>

typedef _Float16 f16;
typedef _Float16 f16x4 __attribute__((ext_vector_type(4)));
typedef _Float16 f16x8 __attribute__((ext_vector_type(8)));
typedef float f32x4 __attribute__((ext_vector_type(4)));
typedef unsigned int u32;
typedef u32 u32x4 __attribute__((ext_vector_type(4)));

__device__ __forceinline__ f32x4 mfma16(f16x8 a, f16x8 b, f32x4 c) {
  return __builtin_amdgcn_mfma_f32_16x16x32_f16(a, b, c, 0, 0, 0);
}

// async global->LDS, 16B per lane. LDS dest is wave-uniform base + lane*16.
__device__ __forceinline__ void gld_lds16(const void* g, void* l) {
  __builtin_amdgcn_global_load_lds(
      (const __attribute__((address_space(1))) void*)g,
      (__attribute__((address_space(3))) void*)l, 16, 0, 0);
}

__device__ __forceinline__ u32 pkrtz(float a, float b) {
  return __builtin_bit_cast(u32, __builtin_amdgcn_cvt_pkrtz(a, b));
}

#define XSWZ(row) (((row) & 7) << 4)

// ---------------- fused f32 -> f16 cast (5 segments) ----------------
__global__ __launch_bounds__(256) void cast5_k(
    const float4* s0, const float4* s1, const float4* s2, const float4* s3,
    const float4* s4, f16x4* d0, f16x4* d1, f16x4* d2, f16x4* d3, f16x4* d4,
    int e0, int e1, int e2, int e3, int e4) {
  int i = blockIdx.x * blockDim.x + threadIdx.x;
  int stride = gridDim.x * blockDim.x;
  for (; i < e4; i += stride) {
    const float4* s = s0; f16x4* d = d0; int base = 0;
    if (i >= e0) { s = s1; d = d1; base = e0; }
    if (i >= e1) { s = s2; d = d2; base = e1; }
    if (i >= e2) { s = s3; d = d3; base = e2; }
    if (i >= e3) { s = s4; d = d4; base = e3; }
    float4 v = s[i - base];
    f16x4 o;
    o.x = (f16)v.x; o.y = (f16)v.y; o.z = (f16)v.z; o.w = (f16)v.w;
    d[i - base] = o;
  }
}

// ---------------- GEMM (128x128, 2-barrier) — used for the KV projection --
template <typename OutT>
__global__ __launch_bounds__(256, 2) void gemm_bt(
    const f16* __restrict__ A, const f16* __restrict__ B, OutT* __restrict__ C,
    int M, int N, int K, float oscale) {
  __shared__ __align__(16) f16 Al[128 * 64];
  __shared__ __align__(16) f16 Bl[128 * 64];
  const int tid = threadIdx.x;
  const int lane = tid & 63;
  const int wave = tid >> 6;
  const int bm = blockIdx.x, bn = blockIdx.y;
  const int wm = wave >> 1, wn = wave & 1;
  f32x4 acc[4][4] = {};

  const size_t ldb = (size_t)K * 2;
  const char* Ab = (const char*)A + (size_t)bm * 128 * ldb;
  const char* Bb = (const char*)B + (size_t)bn * 128 * ldb;

  const int kTiles = K >> 6;
  for (int kt = 0; kt < kTiles; ++kt) {
    const size_t kOff = (size_t)kt << 7;
    __syncthreads();
#pragma unroll
    for (int i = 0; i < 4; ++i) {
      int c = i * 256 + tid;
      int row = c >> 3;
      int colb = ((c & 7) << 4) ^ XSWZ(row);
      gld_lds16(Ab + (size_t)row * ldb + kOff + colb,
                (char*)Al + (i * 256 + wave * 64) * 16);
      gld_lds16(Bb + (size_t)row * ldb + kOff + colb,
                (char*)Bl + (i * 256 + wave * 64) * 16);
    }
    __syncthreads();
#pragma unroll
    for (int kk = 0; kk < 2; ++kk) {
      const int kb = kk * 64 + ((lane >> 4) << 4);
      f16x8 af[4], bf[4];
#pragma unroll
      for (int mf = 0; mf < 4; ++mf) {
        int row = wm * 64 + mf * 16 + (lane & 15);
        af[mf] = *(const f16x8*)((const char*)Al + (row << 7) + (kb ^ XSWZ(row)));
      }
#pragma unroll
      for (int nf = 0; nf < 4; ++nf) {
        int row = wn * 64 + nf * 16 + (lane & 15);
        bf[nf] = *(const f16x8*)((const char*)Bl + (row << 7) + (kb ^ XSWZ(row)));
      }
#pragma unroll
      for (int mf = 0; mf < 4; ++mf)
#pragma unroll
        for (int nf = 0; nf < 4; ++nf)
          acc[mf][nf] = mfma16(af[mf], bf[nf], acc[mf][nf]);
    }
  }
  const int r0 = ((lane >> 4) << 2);
  const int cl = lane & 15;
#pragma unroll
  for (int mf = 0; mf < 4; ++mf)
#pragma unroll
    for (int r = 0; r < 4; ++r) {
      size_t row = (size_t)bm * 128 + wm * 64 + mf * 16 + r0 + r;
#pragma unroll
      for (int nf = 0; nf < 4; ++nf) {
        int col = bn * 128 + wn * 64 + nf * 16 + cl;
        C[row * N + col] = (OutT)(acc[mf][nf][r] * oscale);
      }
    }
}

// ---------------- 256x256 8-phase GEMM (exact R8 version, 76.7us, FROZEN) -
template <typename OutT>
__global__ __launch_bounds__(512, 2) void gemm_bt8(
    const f16* __restrict__ A, const f16* __restrict__ B, OutT* __restrict__ C,
    int M, int N, int K, float oscale) {
  __shared__ __align__(16) char lds[131072];
  const int tid = threadIdx.x;
  const int lane = tid & 63;
  const int wave = tid >> 6;
  const int wm = wave >> 2, wn = wave & 3;
  const int l15 = lane & 15, g = lane >> 4;
  const int bid = blockIdx.x;
  const int bm = (bid & 7) * 4 + ((bid >> 3) & 3);
  const int bn = bid >> 5;

  const size_t ldb = (size_t)K * 2;
  const int r0 = tid >> 2, r1 = 128 + (tid >> 2);
  const int chx = (((tid & 3) ^ ((tid >> 3) & 3)) << 4);
  const char* As0 = (const char*)A + (size_t)(bm * 256 + r0) * ldb + chx;
  const char* As1 = (const char*)A + (size_t)(bm * 256 + r1) * ldb + chx;
  const char* Bs0 = (const char*)B + (size_t)(bn * 256 + r0) * ldb + chx;
  const char* Bs1 = (const char*)B + (size_t)(bn * 256 + r1) * ldb + chx;

  auto stA = [&](int buf, int t, int kh) {
    char* dst = (char*)lds + (buf * 2 + kh) * 16384 + wave * 1024;
    size_t ko = (size_t)t * 128 + (size_t)kh * 64;
    gld_lds16(As0 + ko, dst);
    gld_lds16(As1 + ko, dst + 8192);
  };
  auto stB = [&](int buf, int t, int kh) {
    char* dst = (char*)lds + 65536 + (buf * 2 + kh) * 16384 + wave * 1024;
    size_t ko = (size_t)t * 128 + (size_t)kh * 64;
    gld_lds16(Bs0 + ko, dst);
    gld_lds16(Bs1 + ko, dst + 8192);
  };

  int aoff[8], boff[4];
  const int rsw = (g ^ ((l15 >> 1) & 3)) << 4;
#pragma unroll
  for (int mf = 0; mf < 8; ++mf)
    aoff[mf] = (wm * 128 + mf * 16 + l15) * 64 + rsw;
#pragma unroll
  for (int nf = 0; nf < 4; ++nf)
    boff[nf] = (wn * 64 + nf * 16 + l15) * 64 + rsw;

  f32x4 acc[8][4] = {};

  stA(0, 0, 0); stB(0, 0, 0); stA(0, 0, 1); stB(0, 0, 1);
  stA(1, 1, 0); stB(1, 1, 0); stA(1, 1, 1);
  asm volatile("s_waitcnt vmcnt(6)" ::: "memory");
  __builtin_amdgcn_s_barrier();

  const int nkt = K >> 6;
  for (int T = 0; T < nkt; ++T) {
    const int cur = T & 1;
    const char* A0 = (const char*)lds + (cur * 2 + 0) * 16384;
    const char* A1 = (const char*)lds + (cur * 2 + 1) * 16384;
    const char* B0r = (const char*)lds + 65536 + (cur * 2 + 0) * 16384;
    const char* B1r = (const char*)lds + 65536 + (cur * 2 + 1) * 16384;
    f16x8 a[8], b0, b1;
#pragma unroll
    for (int mf = 0; mf < 8; ++mf) a[mf] = *(const f16x8*)(A0 + aoff[mf]);
    b0 = *(const f16x8*)(B0r + boff[0]);
    b1 = *(const f16x8*)(B0r + boff[1]);
    if (T + 1 < nkt) stB(cur ^ 1, T + 1, 1);
    __builtin_amdgcn_s_barrier();
    __builtin_amdgcn_s_setprio(1);
#pragma unroll
    for (int mf = 0; mf < 8; ++mf) {
      acc[mf][0] = mfma16(a[mf], b0, acc[mf][0]);
      acc[mf][1] = mfma16(a[mf], b1, acc[mf][1]);
    }
    __builtin_amdgcn_s_setprio(0);
    __builtin_amdgcn_s_barrier();
    b0 = *(const f16x8*)(B0r + boff[2]);
    b1 = *(const f16x8*)(B0r + boff[3]);
    if (T + 2 < nkt) stA(cur, T + 2, 0);
    __builtin_amdgcn_s_barrier();
    __builtin_amdgcn_s_setprio(1);
#pragma unroll
    for (int mf = 0; mf < 8; ++mf) {
      acc[mf][2] = mfma16(a[mf], b0, acc[mf][2]);
      acc[mf][3] = mfma16(a[mf], b1, acc[mf][3]);
    }
    __builtin_amdgcn_s_setprio(0);
    __builtin_amdgcn_s_barrier();
#pragma unroll
    for (int mf = 0; mf < 8; ++mf) a[mf] = *(const f16x8*)(A1 + aoff[mf]);
    b0 = *(const f16x8*)(B1r + boff[0]);
    b1 = *(const f16x8*)(B1r + boff[1]);
    if (T + 2 < nkt) stB(cur, T + 2, 0);
    __builtin_amdgcn_s_barrier();
    __builtin_amdgcn_s_setprio(1);
#pragma unroll
    for (int mf = 0; mf < 8; ++mf) {
      acc[mf][0] = mfma16(a[mf], b0, acc[mf][0]);
      acc[mf][1] = mfma16(a[mf], b1, acc[mf][1]);
    }
    __builtin_amdgcn_s_setprio(0);
    __builtin_amdgcn_s_barrier();
    b0 = *(const f16x8*)(B1r + boff[2]);
    b1 = *(const f16x8*)(B1r + boff[3]);
    if (T + 2 < nkt) stA(cur, T + 2, 1);
    if (T < nkt - 2) asm volatile("s_waitcnt vmcnt(6)" ::: "memory");
    else             asm volatile("s_waitcnt vmcnt(0)" ::: "memory");
    __builtin_amdgcn_s_barrier();
    __builtin_amdgcn_s_setprio(1);
#pragma unroll
    for (int mf = 0; mf < 8; ++mf) {
      acc[mf][2] = mfma16(a[mf], b0, acc[mf][2]);
      acc[mf][3] = mfma16(a[mf], b1, acc[mf][3]);
    }
    __builtin_amdgcn_s_setprio(0);
    __builtin_amdgcn_s_barrier();
  }
#pragma unroll
  for (int mf = 0; mf < 8; ++mf)
#pragma unroll
    for (int r = 0; r < 4; ++r) {
      size_t row = (size_t)bm * 256 + wm * 128 + mf * 16 + g * 4 + r;
#pragma unroll
      for (int nf = 0; nf < 4; ++nf) {
        int col = bn * 256 + wn * 64 + nf * 16 + l15;
        C[row * (size_t)N + col] = (OutT)(acc[mf][nf][r] * oscale);
      }
    }
}

// ------- 256x256 quadrant-phase GEMM (m201-faithful reconstruction) -------
// 8 waves 2Mx4N, per-wave C 128x64. LDS = 2buf x 2 M-half x {A,B} 16 KiB
// regions ([128 rows][64k], 128B rows, XSWZ row swizzle = gemm_bt's proven
// layout). Phases = C-quadrants (mfh,nfh): (0,0),(0,1),(1,0),(1,1); each
// reads CURRENT-phase frags pre-barrier (12/4/12/4 b128) and does 16 MFMA
// (4mf x 2nf x kk-chain). Staggered staging by region death: B-half0(T+1)
// @P0, B-half1(T+1)@P1 into buf^1 (dead since T-1.P3); A-halves(T+2)@P3
// into buf (A reads end at P2). Counted vmcnt(4) at P3 (leaves the 4 A
// loads in flight) -> every half complete >=1 barrier before first read.
// Accumulation order per element identical to gemm_bt8 (kk0 then kk1).
template <typename OutT>
__global__ __launch_bounds__(512, 1) void gemm_bt8q(
    const f16* __restrict__ A, const f16* __restrict__ B, OutT* __restrict__ C,
    int M, int N, int K, float oscale) {
  __shared__ __align__(16) char lds[131072];
  const int tid = threadIdx.x;
  const int lane = tid & 63;
  const int wave = tid >> 6;
  const int wm = wave >> 2, wn = wave & 3;
  const int l15 = lane & 15, g = lane >> 4;
  const int bid = blockIdx.x;
  const int bm = (bid & 7) * 4 + ((bid >> 3) & 3);  // XCD-chunked
  const int bn = bid >> 5;

  const size_t ldb = (size_t)K * 2;
  // staging: chunk c = it*512+tid; row = c>>3 (0..127), phys chunk = tid&7;
  // source col byte = (p<<4) ^ XSWZ(row)  (it doesn't affect row&7)
  const int chq = (((tid & 7) ^ ((tid >> 3) & 7)) << 4);
  const int srow = tid >> 3;  // 0..63; +64 for it=1

  auto stage = [&](const f16* X, int rowbase, char* region, int t) {
#pragma unroll
    for (int it = 0; it < 2; ++it) {
      const char* src = (const char*)X +
          (size_t)(rowbase + it * 64 + srow) * ldb + (size_t)t * 128 + chq;
      gld_lds16(src, region + (it * 512 + wave * 64) * 16);
    }
  };
  auto Areg = [&](int buf, int mh) { return (char*)lds + (buf * 2 + mh) * 16384; };
  auto Breg = [&](int buf, int mh) { return (char*)lds + 65536 + (buf * 2 + mh) * 16384; };

  // fragment byte offsets within a region
  int aoff[8][2], boff[4][2];
#pragma unroll
  for (int mf = 0; mf < 8; ++mf) {
    int row = mf * 16 + l15;  // within wave's own A-half (m = wm)
#pragma unroll
    for (int kk = 0; kk < 2; ++kk)
      aoff[mf][kk] = (row << 7) + ((kk * 64 + g * 16) ^ XSWZ(row));
  }
#pragma unroll
  for (int nf = 0; nf < 4; ++nf) {
    int row = (wn & 1) * 64 + nf * 16 + l15;  // within B-half (m = wn>>1)
#pragma unroll
    for (int kk = 0; kk < 2; ++kk)
      boff[nf][kk] = (row << 7) + ((kk * 64 + g * 16) ^ XSWZ(row));
  }

  f32x4 acc[8][4] = {};

  // prologue: tile0 all 4 halves -> buf0 (8 loads); tile1 A halves -> buf1 (4)
  stage(A, bm * 256 + 0,   Areg(0, 0), 0);
  stage(A, bm * 256 + 128, Areg(0, 1), 0);
  stage(B, bn * 256 + 0,   Breg(0, 0), 0);
  stage(B, bn * 256 + 128, Breg(0, 1), 0);
  stage(A, bm * 256 + 0,   Areg(1, 0), 1);
  stage(A, bm * 256 + 128, Areg(1, 1), 1);
  asm volatile("s_waitcnt vmcnt(4)" ::: "memory");
  __builtin_amdgcn_s_barrier();

  const int nkt = K >> 6;
  for (int T = 0; T < nkt; ++T) {
    const int b = T & 1;
    const char* Aw = Areg(b, wm);
    const char* Bw = Breg(b, wn >> 1);
    f16x8 a[4][2], bf[2][2];
    // ---- P0 (mf0-3 x nf0-1): 12 reads; stage B-half0(T+1) -> buf^1
#pragma unroll
    for (int mf = 0; mf < 4; ++mf)
#pragma unroll
      for (int kk = 0; kk < 2; ++kk)
        a[mf][kk] = *(const f16x8*)(Aw + aoff[mf][kk]);
#pragma unroll
    for (int nf = 0; nf < 2; ++nf)
#pragma unroll
      for (int kk = 0; kk < 2; ++kk)
        bf[nf][kk] = *(const f16x8*)(Bw + boff[nf][kk]);
    if (T + 1 < nkt) stage(B, bn * 256 + 0, Breg(b ^ 1, 0), T + 1);
    __builtin_amdgcn_s_barrier();
    __builtin_amdgcn_s_setprio(1);
#pragma unroll
    for (int mf = 0; mf < 4; ++mf)
#pragma unroll
      for (int nf = 0; nf < 2; ++nf) {
        acc[mf][nf] = mfma16(a[mf][0], bf[nf][0], acc[mf][nf]);
        acc[mf][nf] = mfma16(a[mf][1], bf[nf][1], acc[mf][nf]);
      }
    __builtin_amdgcn_s_setprio(0);
    __builtin_amdgcn_s_barrier();
    // ---- P1 (mf0-3 x nf2-3): 4 reads; stage B-half1(T+1) -> buf^1
#pragma unroll
    for (int nf = 0; nf < 2; ++nf)
#pragma unroll
      for (int kk = 0; kk < 2; ++kk)
        bf[nf][kk] = *(const f16x8*)(Bw + boff[2 + nf][kk]);
    if (T + 1 < nkt) stage(B, bn * 256 + 128, Breg(b ^ 1, 1), T + 1);
    __builtin_amdgcn_s_barrier();
    __builtin_amdgcn_s_setprio(1);
#pragma unroll
    for (int mf = 0; mf < 4; ++mf)
#pragma unroll
      for (int nf = 0; nf < 2; ++nf) {
        acc[mf][2 + nf] = mfma16(a[mf][0], bf[nf][0], acc[mf][2 + nf]);
        acc[mf][2 + nf] = mfma16(a[mf][1], bf[nf][1], acc[mf][2 + nf]);
      }
    __builtin_amdgcn_s_setprio(0);
    __builtin_amdgcn_s_barrier();
    // ---- P2 (mf4-7 x nf0-1): 12 reads; no stage
#pragma unroll
    for (int mf = 0; mf < 4; ++mf)
#pragma unroll
      for (int kk = 0; kk < 2; ++kk)
        a[mf][kk] = *(const f16x8*)(Aw + aoff[4 + mf][kk]);
#pragma unroll
    for (int nf = 0; nf < 2; ++nf)
#pragma unroll
      for (int kk = 0; kk < 2; ++kk)
        bf[nf][kk] = *(const f16x8*)(Bw + boff[nf][kk]);
    __builtin_amdgcn_s_barrier();
    __builtin_amdgcn_s_setprio(1);
#pragma unroll
    for (int mf = 0; mf < 4; ++mf)
#pragma unroll
      for (int nf = 0; nf < 2; ++nf) {
        acc[4 + mf][nf] = mfma16(a[mf][0], bf[nf][0], acc[4 + mf][nf]);
        acc[4 + mf][nf] = mfma16(a[mf][1], bf[nf][1], acc[4 + mf][nf]);
      }
    __builtin_amdgcn_s_setprio(0);
    __builtin_amdgcn_s_barrier();
    // ---- P3 (mf4-7 x nf2-3): 4 reads; stage A-halves(T+2) -> buf; vmcnt
#pragma unroll
    for (int nf = 0; nf < 2; ++nf)
#pragma unroll
      for (int kk = 0; kk < 2; ++kk)
        bf[nf][kk] = *(const f16x8*)(Bw + boff[2 + nf][kk]);
    if (T + 2 < nkt) {
      stage(A, bm * 256 + 0,   Areg(b, 0), T + 2);
      stage(A, bm * 256 + 128, Areg(b, 1), T + 2);
    }
    if (T < nkt - 2) asm volatile("s_waitcnt vmcnt(4)" ::: "memory");
    else             asm volatile("s_waitcnt vmcnt(0)" ::: "memory");
    __builtin_amdgcn_s_barrier();
    __builtin_amdgcn_s_setprio(1);
#pragma unroll
    for (int mf = 0; mf < 4; ++mf)
#pragma unroll
      for (int nf = 0; nf < 2; ++nf) {
        acc[4 + mf][2 + nf] = mfma16(a[mf][0], bf[nf][0], acc[4 + mf][2 + nf]);
        acc[4 + mf][2 + nf] = mfma16(a[mf][1], bf[nf][1], acc[4 + mf][2 + nf]);
      }
    __builtin_amdgcn_s_setprio(0);
    __builtin_amdgcn_s_barrier();
  }
  // epilogue: D layout col=lane&15, row=(lane>>4)*4+r
#pragma unroll
  for (int mf = 0; mf < 8; ++mf)
#pragma unroll
    for (int r = 0; r < 4; ++r) {
      size_t row = (size_t)bm * 256 + wm * 128 + mf * 16 + g * 4 + r;
#pragma unroll
      for (int nf = 0; nf < 4; ++nf) {
        int col = bn * 256 + wn * 64 + nf * 16 + l15;
        C[row * (size_t)N + col] = (OutT)(acc[mf][nf][r] * oscale);
      }
    }
}

// token t within 3D block nb -> row in [8192]
__device__ __forceinline__ int tok_row(int nb, int t) {
  int b = nb >> 3;
  int x = (((nb >> 2) & 1) << 3) | (t >> 6);
  int y = (((nb >> 1) & 1) << 3) | ((t >> 3) & 7);
  int z = ((nb & 1) << 3) | (t & 7);
  return (b << 12) | (x << 8) | (y << 4) | z;
}

// ---------------- block attention (R14 version, ~50us) --------------------
__global__ __launch_bounds__(512, 4) void attn3d(
    const f16* __restrict__ Q, const f16* __restrict__ KV, f16* __restrict__ O) {
  __shared__ __align__(16) f16 Kl[2][64 * 64];
  __shared__ __align__(16) f16 Vt[2][64 * 64];
  const int tid = threadIdx.x;
  const int lane = tid & 63;
  const int wave = tid >> 6;
  const int fid = blockIdx.x;
  const int orig = (fid & 7) * 128 + (fid >> 3);
  const int qt = orig & 1, h = (orig >> 1) & 31, nb = orig >> 6;
  const int hk = h >> 2;
  const int l15 = lane & 15;
  const int g = lane >> 4;
  const size_t ldkv = 2048;

  const int pos2 = (((lane & 3) | (((lane >> 4) & 1) << 2) |
                     (((lane >> 2) & 3) << 3) | ((lane >> 5) << 5))) * 2;

  const int krow = tid >> 3;
  const int kcolb = ((tid & 7) << 4) ^ XSWZ(krow);

  f16x8 bq[2][2];
#pragma unroll
  for (int qf = 0; qf < 2; ++qf) {
    const char* qrow = (const char*)Q +
        (size_t)tok_row(nb, qt * 256 + wave * 32 + qf * 16 + l15) * 4096 + h * 128;
#pragma unroll
    for (int kk = 0; kk < 2; ++kk)
      bq[qf][kk] = *(const f16x8*)(qrow + kk * 64 + g * 16);
  }

  {
    gld_lds16((const char*)KV + (size_t)tok_row(nb, krow) * ldkv + hk * 128 + kcolb,
              (char*)Kl[0] + wave * 1024);
    f16x8 vch = *(const f16x8*)((const char*)KV +
        (size_t)tok_row(nb, lane) * ldkv + 1024 + hk * 128 + wave * 16);
    asm volatile("s_waitcnt vmcnt(0)" ::: "memory");
    const int dbase = wave * 8;
#pragma unroll
    for (int j = 0; j < 8; ++j)
      *(f16*)((char*)Vt[0] + ((dbase + j) << 7) + (pos2 ^ (j << 4))) = vch[j];
    __syncthreads();
  }

  f32x4 o[2][4] = {};
  float lacc[2] = {0.f, 0.f};

  for (int kt = 0; kt < 8; ++kt) {
    const int b = kt & 1;
    const char* Kb = (const char*)Kl[b];
    const char* Vb = (const char*)Vt[b];
    f16x8 vch;
    if (kt < 7) {
      gld_lds16((const char*)KV + (size_t)tok_row(nb, (kt + 1) * 64 + krow) * ldkv + hk * 128 + kcolb,
                (char*)Kl[b ^ 1] + wave * 1024);
      vch = *(const f16x8*)((const char*)KV +
          (size_t)tok_row(nb, (kt + 1) * 64 + lane) * ldkv + 1024 + hk * 128 + wave * 16);
    }
    f32x4 s[2][4] = {};
    __builtin_amdgcn_s_setprio(1);
#pragma unroll
    for (int kk = 0; kk < 2; ++kk) {
      const int kb = kk * 64 + (g << 4);
      f16x8 ka[4];
#pragma unroll
      for (int nf = 0; nf < 4; ++nf) {
        int kr = nf * 16 + l15;
        ka[nf] = *(const f16x8*)(Kb + (kr << 7) + (kb ^ XSWZ(kr)));
      }
#pragma unroll
      for (int qf = 0; qf < 2; ++qf)
#pragma unroll
        for (int nf = 0; nf < 4; ++nf)
          s[qf][nf] = mfma16(ka[nf], bq[qf][kk], s[qf][nf]);
    }
    __builtin_amdgcn_s_setprio(0);
#pragma unroll
    for (int qf = 0; qf < 2; ++qf) {
      float ls = 0.f;
#pragma unroll
      for (int nf = 0; nf < 4; ++nf)
#pragma unroll
        for (int r = 0; r < 4; ++r) {
          float p = __builtin_amdgcn_exp2f(s[qf][nf][r]);
          s[qf][nf][r] = p;
          ls += p;
        }
      lacc[qf] += ls;
    }
    __builtin_amdgcn_s_setprio(1);
#pragma unroll
    for (int kh = 0; kh < 2; ++kh) {
      f16x8 va[4];
      const int cb = kh * 64 + g * 16;
#pragma unroll
      for (int df = 0; df < 4; ++df) {
        int d = df * 16 + l15;
        va[df] = *(const f16x8*)(Vb + (d << 7) + (cb ^ XSWZ(d)));
      }
#pragma unroll
      for (int qf = 0; qf < 2; ++qf) {
        u32x4 pw = {pkrtz(s[qf][2 * kh][0], s[qf][2 * kh][1]),
                    pkrtz(s[qf][2 * kh][2], s[qf][2 * kh][3]),
                    pkrtz(s[qf][2 * kh + 1][0], s[qf][2 * kh + 1][1]),
                    pkrtz(s[qf][2 * kh + 1][2], s[qf][2 * kh + 1][3])};
        f16x8 pfh = __builtin_bit_cast(f16x8, pw);
#pragma unroll
        for (int df = 0; df < 4; ++df)
          o[qf][df] = mfma16(va[df], pfh, o[qf][df]);
      }
    }
    __builtin_amdgcn_s_setprio(0);
    if (kt < 7) {
      asm volatile("s_waitcnt vmcnt(0)" ::: "memory");
      const int dbase = wave * 8;
#pragma unroll
      for (int j = 0; j < 8; ++j)
        *(f16*)((char*)Vt[b ^ 1] + ((dbase + j) << 7) + (pos2 ^ (j << 4))) = vch[j];
      __syncthreads();
    }
  }
#pragma unroll
  for (int qf = 0; qf < 2; ++qf) {
    float l = lacc[qf];
    l += __shfl_xor(l, 16);
    l += __shfl_xor(l, 32);
    float inv = 1.f / l;
    int t = qt * 256 + wave * 32 + qf * 16 + l15;
    char* dst = (char*)O + (size_t)tok_row(nb, t) * 4096 + h * 128;
#pragma unroll
    for (int df = 0; df < 4; ++df) {
      f16x4 o4;
#pragma unroll
      for (int r = 0; r < 4; ++r) o4[r] = (f16)(o[qf][df][r] * inv);
      *(f16x4*)(dst + df * 32 + g * 8) = o4;
    }
  }
}

extern "C" void kernel_launch(void* const* d_in, const int* in_sizes, int n_in,
                              void* d_out, int out_size, void* d_ws, size_t ws_size,
                              hipStream_t stream) {
  (void)in_sizes; (void)n_in; (void)out_size; (void)ws_size;
  const float* hs = (const float*)d_in[0];
  const float* Wq = (const float*)d_in[1];
  const float* Wk = (const float*)d_in[2];
  const float* Wv = (const float*)d_in[3];
  const float* Wo = (const float*)d_in[4];
  float* out = (float*)d_out;
  char* ws = (char*)d_ws;

  // workspace layout (100 MB). Wk16/Wv16 contiguous = KV weight (1024 rows).
  f16* hid16 = (f16*)(ws + 0);          // 33554432 B
  f16* Wq16  = (f16*)(ws + 33554432);   // 8388608 B
  f16* Wk16  = (f16*)(ws + 41943040);   // 2097152 B
  f16* Wv16  = (f16*)(ws + 44040192);   // 2097152 B
  f16* Wo16  = (f16*)(ws + 46137344);   // 8388608 B
  f16* Q16   = (f16*)(ws + 54525952);   // 33554432 B
  f16* KV16  = (f16*)(ws + 88080384);   // 16777216 B, [8192][1024] = K|V

  cast5_k<<<2048, 256, 0, stream>>>(
      (const float4*)hs, (const float4*)Wq, (const float4*)Wk,
      (const float4*)Wv, (const float4*)Wo,
      (f16x4*)hid16, (f16x4*)Wq16, (f16x4*)Wk16, (f16x4*)Wv16, (f16x4*)Wo16,
      4194304, 5242880, 5505024, 5767168, 6815744);

  // Q pre-scaled by 0.125*log2(e) so attn softmax is a bare exp2
  gemm_bt8<f16><<<256, 512, 0, stream>>>(hid16, Wq16, Q16, 8192, 2048, 2048,
                                         0.18033688011112042f);  // control (R8)
  gemm_bt<f16><<<dim3(64, 8), 256, 0, stream>>>(hid16, Wk16, KV16, 8192, 1024, 2048, 1.0f);

  attn3d<<<1024, 512, 0, stream>>>(Q16, KV16, hid16);

  // A/B experiment: quadrant-phase schedule on the out-projection only
  gemm_bt8q<float><<<256, 512, 0, stream>>>(hid16, Wo16, out, 8192, 2048, 2048, 1.0f);
}

// Round 16
// 267.228 us; speedup vs baseline: 1.0050x; 1.0050x over previous
//
#include <hip/hip_runtime.h>

typedef _Float16 f16;
typedef _Float16 f16x4 __attribute__((ext_vector_type(4)));
typedef _Float16 f16x8 __attribute__((ext_vector_type(8)));
typedef float f32x4 __attribute__((ext_vector_type(4)));
typedef unsigned int u32;
typedef u32 u32x4 __attribute__((ext_vector_type(4)));

__device__ __forceinline__ f32x4 mfma16(f16x8 a, f16x8 b, f32x4 c) {
  return __builtin_amdgcn_mfma_f32_16x16x32_f16(a, b, c, 0, 0, 0);
}

// async global->LDS, 16B per lane. LDS dest is wave-uniform base + lane*16.
__device__ __forceinline__ void gld_lds16(const void* g, void* l) {
  __builtin_amdgcn_global_load_lds(
      (const __attribute__((address_space(1))) void*)g,
      (__attribute__((address_space(3))) void*)l, 16, 0, 0);
}

__device__ __forceinline__ u32 pkrtz(float a, float b) {
  return __builtin_bit_cast(u32, __builtin_amdgcn_cvt_pkrtz(a, b));
}

#define XSWZ(row) (((row) & 7) << 4)

// ---------------- fused f32 -> f16 cast (5 segments) ----------------
__global__ __launch_bounds__(256) void cast5_k(
    const float4* s0, const float4* s1, const float4* s2, const float4* s3,
    const float4* s4, f16x4* d0, f16x4* d1, f16x4* d2, f16x4* d3, f16x4* d4,
    int e0, int e1, int e2, int e3, int e4) {
  int i = blockIdx.x * blockDim.x + threadIdx.x;
  int stride = gridDim.x * blockDim.x;
  for (; i < e4; i += stride) {
    const float4* s = s0; f16x4* d = d0; int base = 0;
    if (i >= e0) { s = s1; d = d1; base = e0; }
    if (i >= e1) { s = s2; d = d2; base = e1; }
    if (i >= e2) { s = s3; d = d3; base = e2; }
    if (i >= e3) { s = s4; d = d4; base = e3; }
    float4 v = s[i - base];
    f16x4 o;
    o.x = (f16)v.x; o.y = (f16)v.y; o.z = (f16)v.z; o.w = (f16)v.w;
    d[i - base] = o;
  }
}

// ---------------- GEMM (128x128, 2-barrier) — used for the KV projection --
template <typename OutT>
__global__ __launch_bounds__(256, 2) void gemm_bt(
    const f16* __restrict__ A, const f16* __restrict__ B, OutT* __restrict__ C,
    int M, int N, int K, float oscale) {
  __shared__ __align__(16) f16 Al[128 * 64];
  __shared__ __align__(16) f16 Bl[128 * 64];
  const int tid = threadIdx.x;
  const int lane = tid & 63;
  const int wave = tid >> 6;
  const int bm = blockIdx.x, bn = blockIdx.y;
  const int wm = wave >> 1, wn = wave & 1;
  f32x4 acc[4][4] = {};

  const size_t ldb = (size_t)K * 2;
  const char* Ab = (const char*)A + (size_t)bm * 128 * ldb;
  const char* Bb = (const char*)B + (size_t)bn * 128 * ldb;

  const int kTiles = K >> 6;
  for (int kt = 0; kt < kTiles; ++kt) {
    const size_t kOff = (size_t)kt << 7;
    __syncthreads();
#pragma unroll
    for (int i = 0; i < 4; ++i) {
      int c = i * 256 + tid;
      int row = c >> 3;
      int colb = ((c & 7) << 4) ^ XSWZ(row);
      gld_lds16(Ab + (size_t)row * ldb + kOff + colb,
                (char*)Al + (i * 256 + wave * 64) * 16);
      gld_lds16(Bb + (size_t)row * ldb + kOff + colb,
                (char*)Bl + (i * 256 + wave * 64) * 16);
    }
    __syncthreads();
#pragma unroll
    for (int kk = 0; kk < 2; ++kk) {
      const int kb = kk * 64 + ((lane >> 4) << 4);
      f16x8 af[4], bf[4];
#pragma unroll
      for (int mf = 0; mf < 4; ++mf) {
        int row = wm * 64 + mf * 16 + (lane & 15);
        af[mf] = *(const f16x8*)((const char*)Al + (row << 7) + (kb ^ XSWZ(row)));
      }
#pragma unroll
      for (int nf = 0; nf < 4; ++nf) {
        int row = wn * 64 + nf * 16 + (lane & 15);
        bf[nf] = *(const f16x8*)((const char*)Bl + (row << 7) + (kb ^ XSWZ(row)));
      }
#pragma unroll
      for (int mf = 0; mf < 4; ++mf)
#pragma unroll
        for (int nf = 0; nf < 4; ++nf)
          acc[mf][nf] = mfma16(af[mf], bf[nf], acc[mf][nf]);
    }
  }
  const int r0 = ((lane >> 4) << 2);
  const int cl = lane & 15;
#pragma unroll
  for (int mf = 0; mf < 4; ++mf)
#pragma unroll
    for (int r = 0; r < 4; ++r) {
      size_t row = (size_t)bm * 128 + wm * 64 + mf * 16 + r0 + r;
#pragma unroll
      for (int nf = 0; nf < 4; ++nf) {
        int col = bn * 128 + wn * 64 + nf * 16 + cl;
        C[row * N + col] = (OutT)(acc[mf][nf][r] * oscale);
      }
    }
}

// ---------------- 256x256 8-phase GEMM (exact R8 version, 76.7us, FROZEN) -
template <typename OutT>
__global__ __launch_bounds__(512, 2) void gemm_bt8(
    const f16* __restrict__ A, const f16* __restrict__ B, OutT* __restrict__ C,
    int M, int N, int K, float oscale) {
  __shared__ __align__(16) char lds[131072];
  const int tid = threadIdx.x;
  const int lane = tid & 63;
  const int wave = tid >> 6;
  const int wm = wave >> 2, wn = wave & 3;
  const int l15 = lane & 15, g = lane >> 4;
  const int bid = blockIdx.x;
  const int bm = (bid & 7) * 4 + ((bid >> 3) & 3);
  const int bn = bid >> 5;

  const size_t ldb = (size_t)K * 2;
  const int r0 = tid >> 2, r1 = 128 + (tid >> 2);
  const int chx = (((tid & 3) ^ ((tid >> 3) & 3)) << 4);
  const char* As0 = (const char*)A + (size_t)(bm * 256 + r0) * ldb + chx;
  const char* As1 = (const char*)A + (size_t)(bm * 256 + r1) * ldb + chx;
  const char* Bs0 = (const char*)B + (size_t)(bn * 256 + r0) * ldb + chx;
  const char* Bs1 = (const char*)B + (size_t)(bn * 256 + r1) * ldb + chx;

  auto stA = [&](int buf, int t, int kh) {
    char* dst = (char*)lds + (buf * 2 + kh) * 16384 + wave * 1024;
    size_t ko = (size_t)t * 128 + (size_t)kh * 64;
    gld_lds16(As0 + ko, dst);
    gld_lds16(As1 + ko, dst + 8192);
  };
  auto stB = [&](int buf, int t, int kh) {
    char* dst = (char*)lds + 65536 + (buf * 2 + kh) * 16384 + wave * 1024;
    size_t ko = (size_t)t * 128 + (size_t)kh * 64;
    gld_lds16(Bs0 + ko, dst);
    gld_lds16(Bs1 + ko, dst + 8192);
  };

  int aoff[8], boff[4];
  const int rsw = (g ^ ((l15 >> 1) & 3)) << 4;
#pragma unroll
  for (int mf = 0; mf < 8; ++mf)
    aoff[mf] = (wm * 128 + mf * 16 + l15) * 64 + rsw;
#pragma unroll
  for (int nf = 0; nf < 4; ++nf)
    boff[nf] = (wn * 64 + nf * 16 + l15) * 64 + rsw;

  f32x4 acc[8][4] = {};

  stA(0, 0, 0); stB(0, 0, 0); stA(0, 0, 1); stB(0, 0, 1);
  stA(1, 1, 0); stB(1, 1, 0); stA(1, 1, 1);
  asm volatile("s_waitcnt vmcnt(6)" ::: "memory");
  __builtin_amdgcn_s_barrier();

  const int nkt = K >> 6;
  for (int T = 0; T < nkt; ++T) {
    const int cur = T & 1;
    const char* A0 = (const char*)lds + (cur * 2 + 0) * 16384;
    const char* A1 = (const char*)lds + (cur * 2 + 1) * 16384;
    const char* B0r = (const char*)lds + 65536 + (cur * 2 + 0) * 16384;
    const char* B1r = (const char*)lds + 65536 + (cur * 2 + 1) * 16384;
    f16x8 a[8], b0, b1;
#pragma unroll
    for (int mf = 0; mf < 8; ++mf) a[mf] = *(const f16x8*)(A0 + aoff[mf]);
    b0 = *(const f16x8*)(B0r + boff[0]);
    b1 = *(const f16x8*)(B0r + boff[1]);
    if (T + 1 < nkt) stB(cur ^ 1, T + 1, 1);
    __builtin_amdgcn_s_barrier();
    __builtin_amdgcn_s_setprio(1);
#pragma unroll
    for (int mf = 0; mf < 8; ++mf) {
      acc[mf][0] = mfma16(a[mf], b0, acc[mf][0]);
      acc[mf][1] = mfma16(a[mf], b1, acc[mf][1]);
    }
    __builtin_amdgcn_s_setprio(0);
    __builtin_amdgcn_s_barrier();
    b0 = *(const f16x8*)(B0r + boff[2]);
    b1 = *(const f16x8*)(B0r + boff[3]);
    if (T + 2 < nkt) stA(cur, T + 2, 0);
    __builtin_amdgcn_s_barrier();
    __builtin_amdgcn_s_setprio(1);
#pragma unroll
    for (int mf = 0; mf < 8; ++mf) {
      acc[mf][2] = mfma16(a[mf], b0, acc[mf][2]);
      acc[mf][3] = mfma16(a[mf], b1, acc[mf][3]);
    }
    __builtin_amdgcn_s_setprio(0);
    __builtin_amdgcn_s_barrier();
#pragma unroll
    for (int mf = 0; mf < 8; ++mf) a[mf] = *(const f16x8*)(A1 + aoff[mf]);
    b0 = *(const f16x8*)(B1r + boff[0]);
    b1 = *(const f16x8*)(B1r + boff[1]);
    if (T + 2 < nkt) stB(cur, T + 2, 0);
    __builtin_amdgcn_s_barrier();
    __builtin_amdgcn_s_setprio(1);
#pragma unroll
    for (int mf = 0; mf < 8; ++mf) {
      acc[mf][0] = mfma16(a[mf], b0, acc[mf][0]);
      acc[mf][1] = mfma16(a[mf], b1, acc[mf][1]);
    }
    __builtin_amdgcn_s_setprio(0);
    __builtin_amdgcn_s_barrier();
    b0 = *(const f16x8*)(B1r + boff[2]);
    b1 = *(const f16x8*)(B1r + boff[3]);
    if (T + 2 < nkt) stA(cur, T + 2, 1);
    if (T < nkt - 2) asm volatile("s_waitcnt vmcnt(6)" ::: "memory");
    else             asm volatile("s_waitcnt vmcnt(0)" ::: "memory");
    __builtin_amdgcn_s_barrier();
    __builtin_amdgcn_s_setprio(1);
#pragma unroll
    for (int mf = 0; mf < 8; ++mf) {
      acc[mf][2] = mfma16(a[mf], b0, acc[mf][2]);
      acc[mf][3] = mfma16(a[mf], b1, acc[mf][3]);
    }
    __builtin_amdgcn_s_setprio(0);
    __builtin_amdgcn_s_barrier();
  }
#pragma unroll
  for (int mf = 0; mf < 8; ++mf)
#pragma unroll
    for (int r = 0; r < 4; ++r) {
      size_t row = (size_t)bm * 256 + wm * 128 + mf * 16 + g * 4 + r;
#pragma unroll
      for (int nf = 0; nf < 4; ++nf) {
        int col = bn * 256 + wn * 64 + nf * 16 + l15;
        C[row * (size_t)N + col] = (OutT)(acc[mf][nf][r] * oscale);
      }
    }
}

// token t within 3D block nb -> row in [8192]
__device__ __forceinline__ int tok_row(int nb, int t) {
  int b = nb >> 3;
  int x = (((nb >> 2) & 1) << 3) | (t >> 6);
  int y = (((nb >> 1) & 1) << 3) | ((t >> 3) & 7);
  int z = ((nb & 1) << 3) | (t & 7);
  return (b << 12) | (x << 8) | (y << 4) | z;
}

// ---------------- block attention: coalesced-V version --------------------
// R14 structure (qf=2, grid 1024, K/V dbuf, direct-Q) with ONE change: the
// V global->reg load is re-mapped so thread tid loads V[token=tid>>3]
// [16B chunk=tid&7] — a wave covers 8 token rows contiguously (8 line
// requests/wave vs 64 when kv=lane). The scatter writes the IDENTICAL
// (address,value) set into Vt (sigma applied to tid>>3; row&7==j keeps the
// XOR term j<<4), so PV reads and all arithmetic are byte-identical.
__global__ __launch_bounds__(512, 4) void attn3d(
    const f16* __restrict__ Q, const f16* __restrict__ KV, f16* __restrict__ O) {
  __shared__ __align__(16) f16 Kl[2][64 * 64];
  __shared__ __align__(16) f16 Vt[2][64 * 64];
  const int tid = threadIdx.x;
  const int lane = tid & 63;
  const int wave = tid >> 6;
  const int fid = blockIdx.x;
  const int orig = (fid & 7) * 128 + (fid >> 3);
  const int qt = orig & 1, h = (orig >> 1) & 31, nb = orig >> 6;
  const int hk = h >> 2;
  const int l15 = lane & 15;
  const int g = lane >> 4;
  const size_t ldkv = 2048;

  // V staging: thread handles token tok8 = tid>>3, chunk chk = tid&7.
  const int tok8 = tid >> 3;
  const int chk = tid & 7;
  // sigma-permuted column byte position for token tok8
  const int pos2v = (((tok8 & 3) | (((tok8 >> 4) & 1) << 2) |
                      (((tok8 >> 2) & 3) << 3) | ((tok8 >> 5) << 5))) * 2;

  // K-stage addressing (1 gld_lds per thread per tile; already coalesced)
  const int krow = tid >> 3;
  const int kcolb = ((tid & 7) << 4) ^ XSWZ(krow);

  // Q fragments direct from global: lane holds Q[q][d=kk*32+8g+j]
  f16x8 bq[2][2];
#pragma unroll
  for (int qf = 0; qf < 2; ++qf) {
    const char* qrow = (const char*)Q +
        (size_t)tok_row(nb, qt * 256 + wave * 32 + qf * 16 + l15) * 4096 + h * 128;
#pragma unroll
    for (int kk = 0; kk < 2; ++kk)
      bq[qf][kk] = *(const f16x8*)(qrow + kk * 64 + g * 16);
  }

  // prologue: stage tile 0
  {
    gld_lds16((const char*)KV + (size_t)tok_row(nb, krow) * ldkv + hk * 128 + kcolb,
              (char*)Kl[0] + wave * 1024);
    f16x8 vch = *(const f16x8*)((const char*)KV +
        (size_t)tok_row(nb, tok8) * ldkv + 1024 + hk * 128 + chk * 16);
    asm volatile("s_waitcnt vmcnt(0)" ::: "memory");
    const int dbase = chk * 8;
#pragma unroll
    for (int j = 0; j < 8; ++j)
      *(f16*)((char*)Vt[0] + ((dbase + j) << 7) + (pos2v ^ (j << 4))) = vch[j];
    __syncthreads();
  }

  f32x4 o[2][4] = {};
  float lacc[2] = {0.f, 0.f};

  for (int kt = 0; kt < 8; ++kt) {
    const int b = kt & 1;
    const char* Kb = (const char*)Kl[b];
    const char* Vb = (const char*)Vt[b];
    // issue next tile's staging before compute (latency hides under MFMA)
    f16x8 vch;
    if (kt < 7) {
      gld_lds16((const char*)KV + (size_t)tok_row(nb, (kt + 1) * 64 + krow) * ldkv + hk * 128 + kcolb,
                (char*)Kl[b ^ 1] + wave * 1024);
      vch = *(const f16x8*)((const char*)KV +
          (size_t)tok_row(nb, (kt + 1) * 64 + tok8) * ldkv + 1024 + hk * 128 + chk * 16);
    }
    // S^T = K * Q^T : lane holds S[kv=16nf+4g+r][q=l15] per qf
    f32x4 s[2][4] = {};
    __builtin_amdgcn_s_setprio(1);
#pragma unroll
    for (int kk = 0; kk < 2; ++kk) {
      const int kb = kk * 64 + (g << 4);
      f16x8 ka[4];
#pragma unroll
      for (int nf = 0; nf < 4; ++nf) {
        int kr = nf * 16 + l15;
        ka[nf] = *(const f16x8*)(Kb + (kr << 7) + (kb ^ XSWZ(kr)));
      }
#pragma unroll
      for (int qf = 0; qf < 2; ++qf)
#pragma unroll
        for (int nf = 0; nf < 4; ++nf)
          s[qf][nf] = mfma16(ka[nf], bq[qf][kk], s[qf][nf]);
    }
    __builtin_amdgcn_s_setprio(0);
    // softmax-lite: p = 2^s (scale pre-folded into Q)
#pragma unroll
    for (int qf = 0; qf < 2; ++qf) {
      float ls = 0.f;
#pragma unroll
      for (int nf = 0; nf < 4; ++nf)
#pragma unroll
        for (int r = 0; r < 4; ++r) {
          float p = __builtin_amdgcn_exp2f(s[qf][nf][r]);
          s[qf][nf][r] = p;
          ls += p;
        }
      lacc[qf] += ls;
    }
    // O^T += V^T * P^T (slot map kv(g,j)=32kh+4g+(j&3)+16(j>>2))
    __builtin_amdgcn_s_setprio(1);
#pragma unroll
    for (int kh = 0; kh < 2; ++kh) {
      f16x8 va[4];
      const int cb = kh * 64 + g * 16;
#pragma unroll
      for (int df = 0; df < 4; ++df) {
        int d = df * 16 + l15;
        va[df] = *(const f16x8*)(Vb + (d << 7) + (cb ^ XSWZ(d)));
      }
#pragma unroll
      for (int qf = 0; qf < 2; ++qf) {
        u32x4 pw = {pkrtz(s[qf][2 * kh][0], s[qf][2 * kh][1]),
                    pkrtz(s[qf][2 * kh][2], s[qf][2 * kh][3]),
                    pkrtz(s[qf][2 * kh + 1][0], s[qf][2 * kh + 1][1]),
                    pkrtz(s[qf][2 * kh + 1][2], s[qf][2 * kh + 1][3])};
        f16x8 pfh = __builtin_bit_cast(f16x8, pw);
#pragma unroll
        for (int df = 0; df < 4; ++df)
          o[qf][df] = mfma16(va[df], pfh, o[qf][df]);
      }
    }
    __builtin_amdgcn_s_setprio(0);
    // drain staging, scatter V into the other buffer, sync
    if (kt < 7) {
      asm volatile("s_waitcnt vmcnt(0)" ::: "memory");
      const int dbase = chk * 8;
#pragma unroll
      for (int j = 0; j < 8; ++j)
        *(f16*)((char*)Vt[b ^ 1] + ((dbase + j) << 7) + (pos2v ^ (j << 4))) = vch[j];
      __syncthreads();
    }
  }
  // final l reduce (4 g-lanes per q-row) + epilogue
#pragma unroll
  for (int qf = 0; qf < 2; ++qf) {
    float l = lacc[qf];
    l += __shfl_xor(l, 16);
    l += __shfl_xor(l, 32);
    float inv = 1.f / l;
    int t = qt * 256 + wave * 32 + qf * 16 + l15;
    char* dst = (char*)O + (size_t)tok_row(nb, t) * 4096 + h * 128;
#pragma unroll
    for (int df = 0; df < 4; ++df) {
      f16x4 o4;
#pragma unroll
      for (int r = 0; r < 4; ++r) o4[r] = (f16)(o[qf][df][r] * inv);
      *(f16x4*)(dst + df * 32 + g * 8) = o4;
    }
  }
}

extern "C" void kernel_launch(void* const* d_in, const int* in_sizes, int n_in,
                              void* d_out, int out_size, void* d_ws, size_t ws_size,
                              hipStream_t stream) {
  (void)in_sizes; (void)n_in; (void)out_size; (void)ws_size;
  const float* hs = (const float*)d_in[0];
  const float* Wq = (const float*)d_in[1];
  const float* Wk = (const float*)d_in[2];
  const float* Wv = (const float*)d_in[3];
  const float* Wo = (const float*)d_in[4];
  float* out = (float*)d_out;
  char* ws = (char*)d_ws;

  // workspace layout (100 MB). Wk16/Wv16 contiguous = KV weight (1024 rows).
  f16* hid16 = (f16*)(ws + 0);          // 33554432 B
  f16* Wq16  = (f16*)(ws + 33554432);   // 8388608 B
  f16* Wk16  = (f16*)(ws + 41943040);   // 2097152 B
  f16* Wv16  = (f16*)(ws + 44040192);   // 2097152 B
  f16* Wo16  = (f16*)(ws + 46137344);   // 8388608 B
  f16* Q16   = (f16*)(ws + 54525952);   // 33554432 B
  f16* KV16  = (f16*)(ws + 88080384);   // 16777216 B, [8192][1024] = K|V

  cast5_k<<<2048, 256, 0, stream>>>(
      (const float4*)hs, (const float4*)Wq, (const float4*)Wk,
      (const float4*)Wv, (const float4*)Wo,
      (f16x4*)hid16, (f16x4*)Wq16, (f16x4*)Wk16, (f16x4*)Wv16, (f16x4*)Wo16,
      4194304, 5242880, 5505024, 5767168, 6815744);

  // Q pre-scaled by 0.125*log2(e) so attn softmax is a bare exp2
  gemm_bt8<f16><<<256, 512, 0, stream>>>(hid16, Wq16, Q16, 8192, 2048, 2048,
                                         0.18033688011112042f);
  gemm_bt<f16><<<dim3(64, 8), 256, 0, stream>>>(hid16, Wk16, KV16, 8192, 1024, 2048, 1.0f);

  attn3d<<<1024, 512, 0, stream>>>(Q16, KV16, hid16);

  gemm_bt8<float><<<256, 512, 0, stream>>>(hid16, Wo16, out, 8192, 2048, 2048, 1.0f);
}